// Round 16
// baseline (79.024 us; speedup 1.0000x reference)
//
#include <hip/hip_runtime.h>
#include <hip/hip_cooperative_groups.h>
#include <math.h>

#define NTH 256
#define GRID 512
#define CHUNK (4 * NTH)   // pairs per block-chunk (ILP-4)

namespace cg = cooperative_groups;

__device__ __forceinline__ float frcp(float x) { return __builtin_amdgcn_rcpf(x); }
// reciprocal with sign-preserving epsilon (ref's +EPS role); frcp_eps(-d) == -frcp_eps(d)
__device__ __forceinline__ float frcp_eps(float d) {
    float es = __int_as_float((__float_as_int(d) & 0x80000000) | 0x322BCC77); // copysign(1e-8f,d)
    return __builtin_amdgcn_rcpf(d + es);
}

// 4-byte-aligned overlapping 16B loads (boxes at 28B stride)
typedef float float4a __attribute__((ext_vector_type(4), aligned(4)));
__device__ __forceinline__ void load_box(const float* __restrict__ p,
                                         float& cx, float& cy,
                                         float& lw, float& ll, float& yaw) {
    float4a a = *reinterpret_cast<const float4a*>(p);      // fields 0,1,2,3
    float4a b = *reinterpret_cast<const float4a*>(p + 3);  // fields 3,4,5,6
    cx = a.x; cy = a.y; lw = a.w; ll = b.y; yaw = b.w;
}

// Green's-theorem closed-form box-clip area (validated R9/R10, absmax 0).
// NEW: Ltop/Lbot via parallelogram parameter space. Quad = {d + a*u + b*v},
// a,b in [-1,1]. Line y=c: b=(c'-a*uy)/vy -> a-interval from b-bounds; x(a) is
// linear with slope cross(u,v)/vy = hx1*hy1/vy EXACTLY (cancellation-free).
__device__ __forceinline__ float giou_loss_one(const float* __restrict__ b1,
                                               const float* __restrict__ b2)
{
    float cx1, cy1, lw1, ll1, yaw1;
    float cx2, cy2, lw2, ll2, yaw2;
    load_box(b1, cx1, cy1, lw1, ll1, yaw1);
    load_box(b2, cx2, cy2, lw2, ll2, yaw2);
    float w1 = __expf(lw1), l1 = __expf(ll1);
    float w2 = __expf(lw2), l2 = __expf(ll2);

    float s1 = __sinf(yaw1), c1 = __cosf(yaw1);
    float s2 = __sinf(yaw2), c2 = __cosf(yaw2);
    float hx1 = 0.5f * w1, hy1 = 0.5f * l1;
    float hx  = 0.5f * w2, hy  = 0.5f * l2;   // clip-box half-extents

    // world-frame enclosing bbox via exact extent identity |u|+|v|
    float e1x = fmaf(hx1, fabsf(c1), hy1 * fabsf(s1));
    float e1y = fmaf(hx1, fabsf(s1), hy1 * fabsf(c1));
    float e2x = fmaf(hx, fabsf(c2), hy * fabsf(s2));
    float e2y = fmaf(hx, fabsf(s2), hy * fabsf(c2));
    float enc;
    {
        float xmin = fminf(cx1 - e1x, cx2 - e2x);
        float xmax = fmaxf(cx1 + e1x, cx2 + e2x);
        float ymin = fminf(cy1 - e1y, cy2 - e2y);
        float ymax = fmaxf(cy1 + e1y, cy2 + e2y);
        enc = (xmax - xmin) * (ymax - ymin);
    }

    // transform quad1 into box2's frame (box2 -> axis-aligned)
    float sr = s1 * c2 - c1 * s2;       // sin(yaw1-yaw2)
    float cr = c1 * c2 + s1 * s2;       // cos(yaw1-yaw2)
    float tx = cx1 - cx2, ty = cy1 - cy2;
    float dxc =  c2 * tx + s2 * ty;
    float dyc = -s2 * tx + c2 * ty;
    float ux = hx1 * cr, uy = hx1 * sr;
    float vx = -hy1 * sr, vy = hy1 * cr;

    // CCW corners: d-u-v, d+u-v, d+u+v, d-u+v
    float qx[4], qy[4];
    qx[0] = dxc - ux - vx;  qy[0] = dyc - uy - vy;
    qx[1] = dxc + ux - vx;  qy[1] = dyc + uy - vy;
    qx[2] = dxc + ux + vx;  qy[2] = dyc + uy + vy;
    qx[3] = dxc - ux + vx;  qy[3] = dyc - uy + vy;

    // edge vectors: e0=+2u e1=+2v e2=-2u e3=-2v; 4 shared eps-rcps
    float Ux = 2.0f * ux, Uy = 2.0f * uy;
    float Vx = 2.0f * vx, Vy = 2.0f * vy;
    float rUx = frcp_eps(Ux), rUy = frcp_eps(Uy);
    float rVx = frcp_eps(Vx), rVy = frcp_eps(Vy);

    // ---- edge integral: -∮ y dx over in-box parameter intervals ----
    float areaP = 0.0f;
#pragma unroll
    for (int i = 0; i < 4; ++i) {
        float px = qx[i], py = qy[i];
        float dxe  = (i == 0) ? Ux : (i == 1) ? Vx : (i == 2) ? -Ux : -Vx;
        float hdye = (i == 0) ? uy : (i == 1) ? vy : (i == 2) ? -uy : -vy; // 0.5*dye
        float rdx = (i == 0) ? rUx : (i == 1) ? rVx : (i == 2) ? -rUx : -rVx;
        float rdy = (i == 0) ? rUy : (i == 1) ? rVy : (i == 2) ? -rUy : -rVy;
        float ta = (-hx - px) * rdx, tb = (hx - px) * rdx;
        float tc = (-hy - py) * rdy, td = (hy - py) * rdy;
        float t0 = fmaxf(fmaxf(fminf(ta, tb), fminf(tc, td)), 0.0f);
        float t1 = fminf(fminf(fmaxf(ta, tb), fmaxf(tc, td)), 1.0f);
        float dt = fmaxf(t1 - t0, 0.0f);
        areaP -= dxe * dt * fmaf(hdye, t0 + t1, py);
    }

    // ---- closed-form horizontal-line corrections ----
    float area1 = w1 * l1, area2 = w2 * l2;
    float rUy2  = rUy + rUy;              // ~ 1/uy
    float g     = Vx * rVy;               // ~ vx/vy
    float slope = (0.25f * area1) * rUy2 * 0.0f; // placeholder (removed below)
    slope = (0.5f * area1) * rVy;         // cross(u,v)/vy = hx1*hy1/vy, exact
    float Ltop, Lbot;
#pragma unroll
    for (int li = 0; li < 2; ++li) {
        float c  = li ? -hy : hy;
        float cp = c - dyc;
        float a1 = (cp - vy) * rUy2;
        float a2 = (cp + vy) * rUy2;
        float alo = fmaxf(fminf(a1, a2), -1.0f);
        float ahi = fminf(fmaxf(a1, a2),  1.0f);
        float wdt = fmaxf(ahi - alo, 0.0f);        // 0 if line misses quad
        float base = fmaf(cp, g, dxc);
        float xlo = fmaf(alo, slope, base);
        float xhi = fmaf(ahi, slope, base);
        float xm  = fminf(xlo, xhi);
        float xM  = fmaf(fabsf(slope), wdt, xm);   // empty -> xM=xm -> L=0
        float L   = fmaxf(0.0f, fminf(xM, hx) - fmaxf(xm, -hx));
        if (li) Lbot = L; else Ltop = L;
    }
    float inter = fabsf(fmaf(hy, Ltop + Lbot, areaP));

    // giou (areas rotation-invariant; bbox in world frame)
    float uni = area1 + area2 - inter;
    float giou = inter * frcp(uni + 1e-8f) - (enc - uni) * frcp(enc + 1e-8f);
    return 1.0f - giou;
}

// per-block partial over grid-strided chunks (ILP-4 within a chunk)
__device__ __forceinline__ double block_partial(const float* __restrict__ box,
                                                const float* __restrict__ tbox,
                                                int N, int CH)
{
    const int tid = threadIdx.x;
    float loss = 0.0f;
    for (int cid = blockIdx.x; cid < CH; cid += GRID) {
        int base = cid * CHUNK + tid;
#pragma unroll
        for (int k = 0; k < 4; ++k) {
            int gI = base + k * NTH;
            int c = gI < N ? gI : N - 1;                 // branchless tail
            float lk = giou_loss_one(box + (size_t)c * 7, tbox + (size_t)c * 7);
            loss += (gI < N ? lk : 0.0f);
        }
    }
#pragma unroll
    for (int o = 32; o > 0; o >>= 1) loss += __shfl_down(loss, o, 64);
    __shared__ double red[4];
    if ((tid & 63) == 0) red[tid >> 6] = (double)loss;
    __syncthreads();
    return red[0] + red[1] + red[2] + red[3];
}

__device__ __forceinline__ float read_avg(const int* __restrict__ avgp) {
    int ib = *avgp;
    float fb = __int_as_float(ib);
    float av;
    if (ib > 0 && fabsf(fb) < 1e-20f) av = (float)ib;   // int32 payload
    else av = fb;                                        // f32 payload fallback
    if (!(av >= 1.0f)) av = 1.0f;
    return av;
}

// single-dispatch cooperative version: partials -> grid sync -> block 0 reduces
__global__ __launch_bounds__(NTH, 2) void giou_coop(
    const float* __restrict__ box, const float* __restrict__ tbox,
    double* __restrict__ wsum, const int* __restrict__ avgp,
    float* __restrict__ out, int N, int CH)
{
    double p = block_partial(box, tbox, N, CH);
    if (threadIdx.x == 0) wsum[blockIdx.x] = p;
    cg::this_grid().sync();
    if (blockIdx.x == 0) {
        __shared__ double r[NTH];
        int t = threadIdx.x;
        r[t] = wsum[t] + wsum[t + NTH];      // GRID == 2*NTH
        __syncthreads();
#pragma unroll
        for (int s = NTH / 2; s > 0; s >>= 1) {
            if (t < s) r[t] += r[t + s];
            __syncthreads();
        }
        if (t == 0) out[0] = (float)(r[0] / (double)read_avg(avgp));
    }
}

// fallback path (same math, classic 2-dispatch)
__global__ __launch_bounds__(NTH, 2) void giou_part(
    const float* __restrict__ box, const float* __restrict__ tbox,
    double* __restrict__ wsum, int N, int CH)
{
    double p = block_partial(box, tbox, N, CH);
    if (threadIdx.x == 0) wsum[blockIdx.x] = p;
}

__global__ __launch_bounds__(NTH) void finalize_kernel(
    const double* __restrict__ ws, const int* __restrict__ avgp,
    float* __restrict__ out)
{
    __shared__ double r[NTH];
    int t = threadIdx.x;
    r[t] = ws[t] + ws[t + NTH];
    __syncthreads();
#pragma unroll
    for (int s = NTH / 2; s > 0; s >>= 1) {
        if (t < s) r[t] += r[t + s];
        __syncthreads();
    }
    if (t == 0) out[0] = (float)(r[0] / (double)read_avg(avgp));
}

extern "C" void kernel_launch(void* const* d_in, const int* in_sizes, int n_in,
                              void* d_out, int out_size, void* d_ws, size_t ws_size,
                              hipStream_t stream) {
    const float* box  = (const float*)d_in[0];
    const float* tbox = (const float*)d_in[1];
    const int*   avgp = (const int*)d_in[2];
    float* outp = (float*)d_out;
    int N = in_sizes[0] / 7;
    double* ws = (double*)d_ws;
    int CH = (N + CHUNK - 1) / CHUNK;

    void* args[] = { (void*)&box, (void*)&tbox, (void*)&ws, (void*)&avgp,
                     (void*)&outp, (void*)&N, (void*)&CH };
    hipError_t e = hipLaunchCooperativeKernel((const void*)giou_coop,
                                              dim3(GRID), dim3(NTH),
                                              args, 0, stream);
    if (e != hipSuccess) {
        // deterministic fallback: classic 2-dispatch path
        giou_part<<<GRID, NTH, 0, stream>>>(box, tbox, ws, N, CH);
        finalize_kernel<<<1, NTH, 0, stream>>>(ws, avgp, outp);
    }
}

// Round 17
// 18.944 us; speedup vs baseline: 4.1715x; 4.1715x over previous
//
#include <hip/hip_runtime.h>
#include <math.h>

#define NTH 256

__device__ __forceinline__ float frcp(float x) { return __builtin_amdgcn_rcpf(x); }
// reciprocal with sign-preserving epsilon (ref's +EPS role); frcp_eps(-d) == -frcp_eps(d)
__device__ __forceinline__ float frcp_eps(float d) {
    float es = __int_as_float((__float_as_int(d) & 0x80000000) | 0x322BCC77); // copysign(1e-8f,d)
    return __builtin_amdgcn_rcpf(d + es);
}

// 4-byte-aligned overlapping 16B loads (boxes at 28B stride)
typedef float float4a __attribute__((ext_vector_type(4), aligned(4)));
__device__ __forceinline__ void load_box(const float* __restrict__ p,
                                         float& cx, float& cy,
                                         float& lw, float& ll, float& yaw) {
    float4a a = *reinterpret_cast<const float4a*>(p);      // fields 0,1,2,3
    float4a b = *reinterpret_cast<const float4a*>(p + 3);  // fields 3,4,5,6
    cx = a.x; cy = a.y; lw = a.w; ll = b.y; yaw = b.w;
}

// Green's-theorem closed-form box-clip area (validated R9/R10/R16, absmax 0).
// Ltop/Lbot via parallelogram parameter space: quad = {d + a*u + b*v},
// a,b in [-1,1]. Line y=c: a-interval from b-bounds; x(a) linear with slope
// cross(u,v)/vy = hx1*hy1/vy EXACTLY (cancellation-free). VGPR-lean (60 in R16).
__device__ __forceinline__ float giou_loss_one(const float* __restrict__ b1,
                                               const float* __restrict__ b2)
{
    float cx1, cy1, lw1, ll1, yaw1;
    float cx2, cy2, lw2, ll2, yaw2;
    load_box(b1, cx1, cy1, lw1, ll1, yaw1);
    load_box(b2, cx2, cy2, lw2, ll2, yaw2);
    float w1 = __expf(lw1), l1 = __expf(ll1);
    float w2 = __expf(lw2), l2 = __expf(ll2);

    float s1 = __sinf(yaw1), c1 = __cosf(yaw1);
    float s2 = __sinf(yaw2), c2 = __cosf(yaw2);
    float hx1 = 0.5f * w1, hy1 = 0.5f * l1;
    float hx  = 0.5f * w2, hy  = 0.5f * l2;   // clip-box half-extents

    // world-frame enclosing bbox via exact extent identity |u|+|v|
    float e1x = fmaf(hx1, fabsf(c1), hy1 * fabsf(s1));
    float e1y = fmaf(hx1, fabsf(s1), hy1 * fabsf(c1));
    float e2x = fmaf(hx, fabsf(c2), hy * fabsf(s2));
    float e2y = fmaf(hx, fabsf(s2), hy * fabsf(c2));
    float enc;
    {
        float xmin = fminf(cx1 - e1x, cx2 - e2x);
        float xmax = fmaxf(cx1 + e1x, cx2 + e2x);
        float ymin = fminf(cy1 - e1y, cy2 - e2y);
        float ymax = fmaxf(cy1 + e1y, cy2 + e2y);
        enc = (xmax - xmin) * (ymax - ymin);
    }

    // transform quad1 into box2's frame (box2 -> axis-aligned)
    float sr = s1 * c2 - c1 * s2;       // sin(yaw1-yaw2)
    float cr = c1 * c2 + s1 * s2;       // cos(yaw1-yaw2)
    float tx = cx1 - cx2, ty = cy1 - cy2;
    float dxc =  c2 * tx + s2 * ty;
    float dyc = -s2 * tx + c2 * ty;
    float ux = hx1 * cr, uy = hx1 * sr;
    float vx = -hy1 * sr, vy = hy1 * cr;

    // CCW corners: d-u-v, d+u-v, d+u+v, d-u+v
    float qx[4], qy[4];
    qx[0] = dxc - ux - vx;  qy[0] = dyc - uy - vy;
    qx[1] = dxc + ux - vx;  qy[1] = dyc + uy - vy;
    qx[2] = dxc + ux + vx;  qy[2] = dyc + uy + vy;
    qx[3] = dxc - ux + vx;  qy[3] = dyc - uy + vy;

    // edge vectors: e0=+2u e1=+2v e2=-2u e3=-2v; 4 shared eps-rcps
    float Ux = 2.0f * ux, Uy = 2.0f * uy;
    float Vx = 2.0f * vx, Vy = 2.0f * vy;
    float rUx = frcp_eps(Ux), rUy = frcp_eps(Uy);
    float rVx = frcp_eps(Vx), rVy = frcp_eps(Vy);

    // ---- edge integral: -∮ y dx over in-box parameter intervals ----
    float areaP = 0.0f;
#pragma unroll
    for (int i = 0; i < 4; ++i) {
        float px = qx[i], py = qy[i];
        float dxe  = (i == 0) ? Ux : (i == 1) ? Vx : (i == 2) ? -Ux : -Vx;
        float hdye = (i == 0) ? uy : (i == 1) ? vy : (i == 2) ? -uy : -vy; // 0.5*dye
        float rdx = (i == 0) ? rUx : (i == 1) ? rVx : (i == 2) ? -rUx : -rVx;
        float rdy = (i == 0) ? rUy : (i == 1) ? rVy : (i == 2) ? -rUy : -rVy;
        float ta = (-hx - px) * rdx, tb = (hx - px) * rdx;
        float tc = (-hy - py) * rdy, td = (hy - py) * rdy;
        float t0 = fmaxf(fmaxf(fminf(ta, tb), fminf(tc, td)), 0.0f);
        float t1 = fminf(fminf(fmaxf(ta, tb), fmaxf(tc, td)), 1.0f);
        float dt = fmaxf(t1 - t0, 0.0f);
        areaP -= dxe * dt * fmaf(hdye, t0 + t1, py);
    }

    // ---- closed-form horizontal-line corrections ----
    float area1 = w1 * l1, area2 = w2 * l2;
    float rUy2  = rUy + rUy;              // ~ 1/uy
    float g     = Vx * rVy;               // ~ vx/vy
    float slope = (0.5f * area1) * rVy;   // cross(u,v)/vy = hx1*hy1/vy, exact
    float Ltop, Lbot;
#pragma unroll
    for (int li = 0; li < 2; ++li) {
        float c  = li ? -hy : hy;
        float cp = c - dyc;
        float a1 = (cp - vy) * rUy2;
        float a2 = (cp + vy) * rUy2;
        float alo = fmaxf(fminf(a1, a2), -1.0f);
        float ahi = fminf(fmaxf(a1, a2),  1.0f);
        float wdt = fmaxf(ahi - alo, 0.0f);        // 0 if line misses quad
        float base = fmaf(cp, g, dxc);
        float xlo = fmaf(alo, slope, base);
        float xhi = fmaf(ahi, slope, base);
        float xm  = fminf(xlo, xhi);
        float xM  = fmaf(fabsf(slope), wdt, xm);   // empty -> xM=xm -> L=0
        float L   = fmaxf(0.0f, fminf(xM, hx) - fmaxf(xm, -hx));
        if (li) Lbot = L; else Ltop = L;
    }
    float inter = fabsf(fmaf(hy, Ltop + Lbot, areaP));

    // giou (areas rotation-invariant; bbox in world frame)
    float uni = area1 + area2 - inter;
    float giou = inter * frcp(uni + 1e-8f) - (enc - uni) * frcp(enc + 1e-8f);
    return 1.0f - giou;
}

__global__ __launch_bounds__(NTH) void giou_kernel(
    const float* __restrict__ box, const float* __restrict__ tbox,
    double* __restrict__ wsum, int N)
{
    __shared__ double red[4];
    const int tid = threadIdx.x;
    const int base = blockIdx.x * (4 * NTH) + tid;

    // branchless tail: clamp index, select-to-zero
    float loss = 0.0f;
#pragma unroll
    for (int k = 0; k < 4; ++k) {
        int g = base + k * NTH;
        int c = g < N ? g : N - 1;
        float lk = giou_loss_one(box + (size_t)c * 7, tbox + (size_t)c * 7);
        loss += (g < N ? lk : 0.0f);
    }

    // reduction: f32 wave shuffle -> f64 block partial -> per-block store
#pragma unroll
    for (int o = 32; o > 0; o >>= 1) loss += __shfl_down(loss, o, 64);

    if ((tid & 63) == 0) red[tid >> 6] = (double)loss;
    __syncthreads();
    if (tid == 0)
        wsum[blockIdx.x] = red[0] + red[1] + red[2] + red[3];  // no memset, no atomic
}

__global__ __launch_bounds__(NTH) void finalize_kernel(
    const double* __restrict__ ws, int nblk,
    const int* __restrict__ avgp, float* __restrict__ out)
{
    __shared__ double r[NTH];
    int t = threadIdx.x;
    double v = 0.0;
    for (int i = t; i < nblk; i += NTH) v += ws[i];
    r[t] = v;
    __syncthreads();
#pragma unroll
    for (int s = NTH / 2; s > 0; s >>= 1) {
        if (t < s) r[t] += r[t + s];
        __syncthreads();
    }
    if (t == 0) {
        int ib = *avgp;
        float fb = __int_as_float(ib);
        float av;
        if (ib > 0 && fabsf(fb) < 1e-20f) av = (float)ib;   // int32 payload
        else av = fb;                                        // f32 payload fallback
        if (!(av >= 1.0f)) av = 1.0f;
        out[0] = (float)(r[0] / (double)av);
    }
}

extern "C" void kernel_launch(void* const* d_in, const int* in_sizes, int n_in,
                              void* d_out, int out_size, void* d_ws, size_t ws_size,
                              hipStream_t stream) {
    const float* box  = (const float*)d_in[0];
    const float* tbox = (const float*)d_in[1];
    const int*   avgp = (const int*)d_in[2];
    int N = in_sizes[0] / 7;
    double* ws = (double*)d_ws;

    int blocks = (N + 4 * NTH - 1) / (4 * NTH);
    giou_kernel<<<blocks, NTH, 0, stream>>>(box, tbox, ws, N);
    finalize_kernel<<<1, NTH, 0, stream>>>(ws, blocks, avgp, (float*)d_out);
}

// Round 18
// 18.295 us; speedup vs baseline: 4.3194x; 1.0354x over previous
//
#include <hip/hip_runtime.h>
#include <math.h>

#define NTH 256
#define ILP 8

__device__ __forceinline__ float frcp(float x) { return __builtin_amdgcn_rcpf(x); }
// reciprocal with sign-preserving epsilon (ref's +EPS role); frcp_eps(-d) == -frcp_eps(d)
__device__ __forceinline__ float frcp_eps(float d) {
    float es = __int_as_float((__float_as_int(d) & 0x80000000) | 0x322BCC77); // copysign(1e-8f,d)
    return __builtin_amdgcn_rcpf(d + es);
}

// 4-byte-aligned overlapping 16B loads (boxes at 28B stride)
typedef float float4a __attribute__((ext_vector_type(4), aligned(4)));
__device__ __forceinline__ void load_box(const float* __restrict__ p,
                                         float& cx, float& cy,
                                         float& lw, float& ll, float& yaw) {
    float4a a = *reinterpret_cast<const float4a*>(p);      // fields 0,1,2,3
    float4a b = *reinterpret_cast<const float4a*>(p + 3);  // fields 3,4,5,6
    cx = a.x; cy = a.y; lw = a.w; ll = b.y; yaw = b.w;
}

// Green's-theorem closed-form box-clip area (validated R9/R10/R16/R17, absmax 0).
// Ltop/Lbot via parallelogram parameter space (VGPR-lean: 60 in R16 build).
__device__ __forceinline__ float giou_loss_one(const float* __restrict__ b1,
                                               const float* __restrict__ b2)
{
    float cx1, cy1, lw1, ll1, yaw1;
    float cx2, cy2, lw2, ll2, yaw2;
    load_box(b1, cx1, cy1, lw1, ll1, yaw1);
    load_box(b2, cx2, cy2, lw2, ll2, yaw2);
    float w1 = __expf(lw1), l1 = __expf(ll1);
    float w2 = __expf(lw2), l2 = __expf(ll2);

    float s1 = __sinf(yaw1), c1 = __cosf(yaw1);
    float s2 = __sinf(yaw2), c2 = __cosf(yaw2);
    float hx1 = 0.5f * w1, hy1 = 0.5f * l1;
    float hx  = 0.5f * w2, hy  = 0.5f * l2;   // clip-box half-extents

    // world-frame enclosing bbox via exact extent identity |u|+|v|
    float e1x = fmaf(hx1, fabsf(c1), hy1 * fabsf(s1));
    float e1y = fmaf(hx1, fabsf(s1), hy1 * fabsf(c1));
    float e2x = fmaf(hx, fabsf(c2), hy * fabsf(s2));
    float e2y = fmaf(hx, fabsf(s2), hy * fabsf(c2));
    float enc;
    {
        float xmin = fminf(cx1 - e1x, cx2 - e2x);
        float xmax = fmaxf(cx1 + e1x, cx2 + e2x);
        float ymin = fminf(cy1 - e1y, cy2 - e2y);
        float ymax = fmaxf(cy1 + e1y, cy2 + e2y);
        enc = (xmax - xmin) * (ymax - ymin);
    }

    // transform quad1 into box2's frame (box2 -> axis-aligned)
    float sr = s1 * c2 - c1 * s2;       // sin(yaw1-yaw2)
    float cr = c1 * c2 + s1 * s2;       // cos(yaw1-yaw2)
    float tx = cx1 - cx2, ty = cy1 - cy2;
    float dxc =  c2 * tx + s2 * ty;
    float dyc = -s2 * tx + c2 * ty;
    float ux = hx1 * cr, uy = hx1 * sr;
    float vx = -hy1 * sr, vy = hy1 * cr;

    // CCW corners: d-u-v, d+u-v, d+u+v, d-u+v
    float qx[4], qy[4];
    qx[0] = dxc - ux - vx;  qy[0] = dyc - uy - vy;
    qx[1] = dxc + ux - vx;  qy[1] = dyc + uy - vy;
    qx[2] = dxc + ux + vx;  qy[2] = dyc + uy + vy;
    qx[3] = dxc - ux + vx;  qy[3] = dyc - uy + vy;

    // edge vectors: e0=+2u e1=+2v e2=-2u e3=-2v; 4 shared eps-rcps
    float Ux = 2.0f * ux, Uy = 2.0f * uy;
    float Vx = 2.0f * vx, Vy = 2.0f * vy;
    float rUx = frcp_eps(Ux), rUy = frcp_eps(Uy);
    float rVx = frcp_eps(Vx), rVy = frcp_eps(Vy);

    // ---- edge integral: -∮ y dx over in-box parameter intervals ----
    float areaP = 0.0f;
#pragma unroll
    for (int i = 0; i < 4; ++i) {
        float px = qx[i], py = qy[i];
        float dxe  = (i == 0) ? Ux : (i == 1) ? Vx : (i == 2) ? -Ux : -Vx;
        float hdye = (i == 0) ? uy : (i == 1) ? vy : (i == 2) ? -uy : -vy; // 0.5*dye
        float rdx = (i == 0) ? rUx : (i == 1) ? rVx : (i == 2) ? -rUx : -rVx;
        float rdy = (i == 0) ? rUy : (i == 1) ? rVy : (i == 2) ? -rUy : -rVy;
        float ta = (-hx - px) * rdx, tb = (hx - px) * rdx;
        float tc = (-hy - py) * rdy, td = (hy - py) * rdy;
        float t0 = fmaxf(fmaxf(fminf(ta, tb), fminf(tc, td)), 0.0f);
        float t1 = fminf(fminf(fmaxf(ta, tb), fmaxf(tc, td)), 1.0f);
        float dt = fmaxf(t1 - t0, 0.0f);
        areaP -= dxe * dt * fmaf(hdye, t0 + t1, py);
    }

    // ---- closed-form horizontal-line corrections ----
    float area1 = w1 * l1, area2 = w2 * l2;
    float rUy2  = rUy + rUy;              // ~ 1/uy
    float g     = Vx * rVy;               // ~ vx/vy
    float slope = (0.5f * area1) * rVy;   // cross(u,v)/vy = hx1*hy1/vy, exact
    float Ltop, Lbot;
#pragma unroll
    for (int li = 0; li < 2; ++li) {
        float c  = li ? -hy : hy;
        float cp = c - dyc;
        float a1 = (cp - vy) * rUy2;
        float a2 = (cp + vy) * rUy2;
        float alo = fmaxf(fminf(a1, a2), -1.0f);
        float ahi = fminf(fmaxf(a1, a2),  1.0f);
        float wdt = fmaxf(ahi - alo, 0.0f);        // 0 if line misses quad
        float base = fmaf(cp, g, dxc);
        float xlo = fmaf(alo, slope, base);
        float xhi = fmaf(ahi, slope, base);
        float xm  = fminf(xlo, xhi);
        float xM  = fmaf(fabsf(slope), wdt, xm);   // empty -> xM=xm -> L=0
        float L   = fmaxf(0.0f, fminf(xM, hx) - fmaxf(xm, -hx));
        if (li) Lbot = L; else Ltop = L;
    }
    float inter = fabsf(fmaf(hy, Ltop + Lbot, areaP));

    // giou (areas rotation-invariant; bbox in world frame)
    float uni = area1 + area2 - inter;
    float giou = inter * frcp(uni + 1e-8f) - (enc - uni) * frcp(enc + 1e-8f);
    return 1.0f - giou;
}

__global__ __launch_bounds__(NTH) void giou_kernel(
    const float* __restrict__ box, const float* __restrict__ tbox,
    double* __restrict__ wsum, int N)
{
    __shared__ double red[4];
    const int tid = threadIdx.x;
    const int base = blockIdx.x * (ILP * NTH) + tid;

    // branchless tail: clamp index, select-to-zero; 8 independent chains
    float loss = 0.0f;
#pragma unroll
    for (int k = 0; k < ILP; ++k) {
        int g = base + k * NTH;
        int c = g < N ? g : N - 1;
        float lk = giou_loss_one(box + (size_t)c * 7, tbox + (size_t)c * 7);
        loss += (g < N ? lk : 0.0f);
    }

    // reduction: f32 wave shuffle -> f64 block partial -> per-block store
#pragma unroll
    for (int o = 32; o > 0; o >>= 1) loss += __shfl_down(loss, o, 64);

    if ((tid & 63) == 0) red[tid >> 6] = (double)loss;
    __syncthreads();
    if (tid == 0)
        wsum[blockIdx.x] = red[0] + red[1] + red[2] + red[3];  // no memset, no atomic
}

__global__ __launch_bounds__(NTH) void finalize_kernel(
    const double* __restrict__ ws, int nblk,
    const int* __restrict__ avgp, float* __restrict__ out)
{
    __shared__ double r[NTH];
    int t = threadIdx.x;
    double v = 0.0;
    for (int i = t; i < nblk; i += NTH) v += ws[i];
    r[t] = v;
    __syncthreads();
#pragma unroll
    for (int s = NTH / 2; s > 0; s >>= 1) {
        if (t < s) r[t] += r[t + s];
        __syncthreads();
    }
    if (t == 0) {
        int ib = *avgp;
        float fb = __int_as_float(ib);
        float av;
        if (ib > 0 && fabsf(fb) < 1e-20f) av = (float)ib;   // int32 payload
        else av = fb;                                        // f32 payload fallback
        if (!(av >= 1.0f)) av = 1.0f;
        out[0] = (float)(r[0] / (double)av);
    }
}

extern "C" void kernel_launch(void* const* d_in, const int* in_sizes, int n_in,
                              void* d_out, int out_size, void* d_ws, size_t ws_size,
                              hipStream_t stream) {
    const float* box  = (const float*)d_in[0];
    const float* tbox = (const float*)d_in[1];
    const int*   avgp = (const int*)d_in[2];
    int N = in_sizes[0] / 7;
    double* ws = (double*)d_ws;

    int blocks = (N + ILP * NTH - 1) / (ILP * NTH);
    giou_kernel<<<blocks, NTH, 0, stream>>>(box, tbox, ws, N);
    finalize_kernel<<<1, NTH, 0, stream>>>(ws, blocks, avgp, (float*)d_out);
}